// Round 7
// baseline (214.825 us; speedup 1.0000x reference)
//
#include <hip/hip_runtime.h>
#include <math.h>

#define BB 8
#define NN 40000
#define CC 80
#define TOPK 500
#define MM (BB*TOPK)          // 4000
#define NBINS 4096
#define BIN_LO (-8.0f)
#define BIN_SCALE 256.0f      // bins per unit -> covers [-8, 8)
#define CAP 4096
#define NGROUPS (CC*BB)       // 640
#define THR_CONF_F 0.05f
#define THR_NMS_F 0.5f
#define THR_LOGIT 3.4f        // prefilter: 500th logit ~3.61+-0.011 -> 18-sigma margin;
                              // k_select falls back to exact histogram path if violated

__device__ __forceinline__ int bin_of(float x){
  float f = (x - BIN_LO) * BIN_SCALE;
  int b = (int)floorf(f);
  b = b < 0 ? 0 : b;
  b = b > (NBINS-1) ? (NBINS-1) : b;
  return b;
}

__device__ __forceinline__ unsigned long long make_key(float lg, int idx){
  // correctly-rounded f32 sigmoid via double exp: matches XLA's faithful expf
  // bit pattern for the tie structure jax.lax.top_k sees.
  float e = (float)exp(-(double)lg);
  float s = 1.0f/(1.0f+e);
  return ((unsigned long long)__float_as_uint(s) << 16)
       | (unsigned long long)(65535 - idx);
}

// Kernel 1: 4 lanes per row, coalesced 64B-per-instruction reads. Writes
// logitv/label (fallback + emit lookup) and block-compacts prefiltered
// candidates with ONE global atomic per block (64 rows, single batch).
__global__ void k_score(const float* __restrict__ pconf,
                        float* __restrict__ logitv, int* __restrict__ label,
                        int* __restrict__ cnt, unsigned long long* __restrict__ cand){
  int tid = threadIdx.x;
  int g   = blockIdx.x*256 + tid;           // 1.28M threads total
  int row = g >> 2;
  int sub = g & 3;
  __shared__ unsigned long long lkey[64];
  __shared__ int lcnt, lbase;
  if(tid == 0) lcnt = 0;
  __syncthreads();

  const float4* p = (const float4*)pconf + (size_t)row*20 + sub;
  float4 v0 = p[0], v1 = p[4], v2 = p[8], v3 = p[12], v4 = p[16];
  float best = -3.4e38f; int bi = 0;
  int c0 = sub*4;
  #define CHK(vv,it) { \
    int base = c0 + (it)*16; \
    if(vv.x>best){best=vv.x;bi=base+0;} \
    if(vv.y>best){best=vv.y;bi=base+1;} \
    if(vv.z>best){best=vv.z;bi=base+2;} \
    if(vv.w>best){best=vv.w;bi=base+3;} }
  CHK(v0,0) CHK(v1,1) CHK(v2,2) CHK(v3,3) CHK(v4,4)
  #undef CHK
  #pragma unroll
  for(int d=1; d<4; d<<=1){
    float ov = __shfl_xor(best, d, 64);
    int   oi = __shfl_xor(bi,   d, 64);
    if(ov > best || (ov == best && oi < bi)){ best = ov; bi = oi; }
  }
  int b = row / NN;                          // block-uniform (64 | 40000)
  if(sub == 0){
    logitv[row] = best; label[row] = bi;
    if(best > THR_LOGIT){
      int pos = atomicAdd(&lcnt, 1);
      lkey[pos] = make_key(best, row - b*NN);
    }
  }
  __syncthreads();
  int n = lcnt;
  if(tid == 0 && n > 0) lbase = atomicAdd(&cnt[b], n);
  __syncthreads();
  for(int i=tid; i<n; i+=256){
    int pos = lbase + i;
    if(pos < CAP) cand[(size_t)b*CAP + pos] = lkey[i];
  }
}

// Kernel 2: per-batch select + emit. Fast path: rank the prefiltered cand
// keys. Fallback (cnt out of [TOPK,CAP]): exact histogram -> threshold ->
// compact, identical selection semantics. Key desc = score desc, index asc
// == jax.lax.top_k ordering incl. f32 tie groups.
__global__ void __launch_bounds__(1024)
k_select(const float* __restrict__ logitv, const int* __restrict__ label,
         const float* __restrict__ pboxes, const int* __restrict__ cnt,
         const unsigned long long* __restrict__ cand,
         float* __restrict__ out,
         float* __restrict__ cbox, int* __restrict__ cgid,
         float* __restrict__ cscore, int* __restrict__ maxval){
  int b = blockIdx.x;
  int t = threadIdx.x;
  __shared__ unsigned long long keys[CAP];
  __shared__ int h[NBINS];
  __shared__ int ss[1024];
  __shared__ int stbin, scnt, smax;
  if(t==0) smax = 0;                 // true max positive -> 0-init safe

  int n = cnt[b];
  if(n >= TOPK && n <= CAP){
    // --- fast path: load prefiltered keys ---
    for(int i=t; i<n; i+=1024) keys[i] = cand[(size_t)b*CAP + i];
    __syncthreads();
  } else {
    // --- fallback: exact histogram selection from logitv ---
    for(int i=t; i<NBINS; i+=1024) h[i] = 0;
    if(t==0) scnt = 0;
    __syncthreads();
    const float4* lv4 = (const float4*)(logitv + (size_t)b*NN);
    for(int i=t; i<NN/4; i+=1024){
      float4 v = lv4[i];
      atomicAdd(&h[bin_of(v.x)], 1);
      atomicAdd(&h[bin_of(v.y)], 1);
      atomicAdd(&h[bin_of(v.z)], 1);
      atomicAdd(&h[bin_of(v.w)], 1);
    }
    __syncthreads();
    int c0 = t*4;
    int cs = h[c0] + h[c0+1] + h[c0+2] + h[c0+3];
    ss[t] = cs;
    __syncthreads();
    for(int off=1; off<1024; off<<=1){
      int v = (t+off < 1024) ? ss[t+off] : 0;
      __syncthreads();
      ss[t] += v;
      __syncthreads();
    }
    int sufExcl = (t < 1023) ? ss[t+1] : 0;
    if(sufExcl < TOPK && sufExcl + cs >= TOPK){
      int cum = sufExcl; int tb = 0;
      for(int k=3; k>=0; k--){
        cum += h[c0+k];
        if(cum >= TOPK){ tb = c0+k; break; }
      }
      tb -= 2; if(tb < 0) tb = 0;
      stbin = tb;
    }
    __syncthreads();
    int tb = stbin;
    const float* lv = logitv + (size_t)b*NN;
    for(int idx=t; idx<NN; idx+=1024){
      float lg = lv[idx];
      if(bin_of(lg) >= tb){
        int pos = atomicAdd(&scnt, 1);
        if(pos < CAP) keys[pos] = make_key(lg, idx);
      }
    }
    __syncthreads();
    n = scnt; if(n > CAP) n = CAP;
  }

  // --- rank (keys unique -> permutation) + emit ---
  for(int i=t; i<n; i+=1024){
    unsigned long long ki = keys[i];
    int rank = 0;
    for(int j=0; j<n; j++) rank += (keys[j] > ki) ? 1 : 0;
    if(rank < TOPK){
      int idx = 65535 - (int)(ki & 0xFFFFULL);
      int row = b*NN + idx;
      float s = __uint_as_float((unsigned int)(ki >> 16));
      int lab = label[row];
      float4 bv = *(const float4*)(pboxes + (size_t)row*4);
      int m = b*TOPK + rank;
      out[m] = (float)b;                       // ids_batch1
      float* ob = out + MM + (size_t)m*4;      // p_boxes1
      ob[0]=bv.x; ob[1]=bv.y; ob[2]=bv.z; ob[3]=bv.w;
      out[5*MM + m] = (float)lab;              // p_labels1
      out[6*MM + m] = s;                       // p_scores1
      cbox[m*4+0]=bv.x; cbox[m*4+1]=bv.y; cbox[m*4+2]=bv.z; cbox[m*4+3]=bv.w;
      cgid[m] = lab*BB + b;                    // ref key = label*B + batch
      cscore[m] = s;
      float mx = fmaxf(fmaxf(bv.x,bv.y), fmaxf(bv.z,bv.w));
      atomicMax(&smax, __float_as_int(mx));    // positive max -> int cmp ok
    }
  }
  __syncthreads();
  if(t==0) maxval[b] = smax;
}

// Kernel 3: per-(label,batch)-group greedy NMS, one wave per group. Cross-group
// IoU exactly 0 (offset gap), so global greedy == per-group greedy in
// within-group flat order. Groups are batch-pure: scan only this batch's 500.
__global__ void __launch_bounds__(64)
k_nms(const float* __restrict__ cbox, const int* __restrict__ cgid,
      const float* __restrict__ cscore, const int* __restrict__ maxval,
      float* __restrict__ out_keep){
  int g = blockIdx.x;
  int lane = threadIdx.x;
  __shared__ float bx[TOPK][4];
  __shared__ float area[TOPK];
  __shared__ int   mid[TOPK];
  __shared__ unsigned char keepf[TOPK];
  int mb = maxval[0];
  #pragma unroll
  for(int k=1;k<BB;k++) mb = max(mb, maxval[k]); // positive floats: int cmp ok
  float mc  = __int_as_float(mb);
  float off = (float)g * (mc + 1.0f);
  int b = g & (BB-1);                    // g = lab*BB + b
  int lo = b*TOPK, hi = lo + TOPK;

  int count = 0;
  for(int base=lo; base<hi; base+=64){
    int m = base + lane;
    bool match = (m < hi) && (cgid[m] == g);
    unsigned long long mk = __ballot(match);
    if(match){
      int p = count + __popcll(mk & ((1ULL<<lane)-1ULL));
      float x1 = cbox[m*4+0] + off;
      float y1 = cbox[m*4+1] + off;
      float x2 = cbox[m*4+2] + off;
      float y2 = cbox[m*4+3] + off;
      bx[p][0]=x1; bx[p][1]=y1; bx[p][2]=x2; bx[p][3]=y2;
      area[p] = (x2-x1)*(y2-y1);         // area of OFFSET box, like ref
      mid[p] = m;
      keepf[p] = (cscore[m] > THR_CONF_F) ? 1 : 0;
    }
    count += __popcll(mk);
  }
  __syncthreads();

  for(int i=0; i<count; i++){
    if(keepf[i]){
      float ix1=bx[i][0], iy1=bx[i][1], ix2=bx[i][2], iy2=bx[i][3], ia=area[i];
      for(int j=i+1+lane; j<count; j+=64){
        if(keepf[j]){
          float lx = fmaxf(ix1, bx[j][0]);
          float ly = fmaxf(iy1, bx[j][1]);
          float rx = fminf(ix2, bx[j][2]);
          float ry = fminf(iy2, bx[j][3]);
          float w = fmaxf(rx-lx, 0.0f), h = fmaxf(ry-ly, 0.0f);
          float inter = w*h;
          float uni = ia + area[j] - inter;     // (a_i + a_j) - inter, ref order
          float iou = inter / fmaxf(uni, 1e-9f);
          if(iou > THR_NMS_F) keepf[j] = 0;
        }
      }
    }
    __syncthreads();
  }
  for(int p=lane; p<count; p+=64)
    out_keep[mid[p]] = keepf[p] ? 1.0f : 0.0f;
}

extern "C" void kernel_launch(void* const* d_in, const int* in_sizes, int n_in,
                              void* d_out, int out_size, void* d_ws, size_t ws_size,
                              hipStream_t stream) {
  const float* pconf  = (const float*)d_in[0];
  const float* pboxes = (const float*)d_in[1];
  float* out = (float*)d_out;
  char* ws = (char*)d_ws;

  // ws layout (bytes)
  int*   cnt     = (int*)  (ws + 0);             // 8*4 = 32 (memset to 0)
  float* logitv  = (float*)(ws + 128);           // 320000*4 = 1280000
  int*   label   = (int*)  (ws + 1280128);       // 320000*4 = 1280000
  unsigned long long* cand = (unsigned long long*)(ws + 2560128); // 8*4096*8
  float* cbox    = (float*)(ws + 2822272);       // 4000*4*4 = 64000
  int*   cgid    = (int*)  (ws + 2886272);       // 4000*4
  float* cscore  = (float*)(ws + 2902272);       // 4000*4
  int*   maxval  = (int*)  (ws + 2918272);       // 8*4      (end 2918304)

  hipMemsetAsync(ws, 0, 32, stream);             // cnt only

  k_score <<<(BB*NN*4)/256, 256, 0, stream>>>(pconf, logitv, label, cnt, cand);
  k_select<<<BB, 1024, 0, stream>>>(logitv, label, pboxes, cnt, cand, out,
                                    cbox, cgid, cscore, maxval);
  k_nms   <<<NGROUPS, 64, 0, stream>>>(cbox, cgid, cscore, maxval, out + 7*MM);
}